// Round 1
// baseline (648.454 us; speedup 1.0000x reference)
//
#include <hip/hip_runtime.h>

// CausalLinearAttention (linear attention, elu+1 feature map), fp32 baseline.
// N=4, L=8192, H=16, E=D=64.
// 3-pass segment-parallel scan:
//   pass1: per-(n,h,seg) partial K^T V (64x64) and sum(K) (64)
//   pass2: exclusive prefix over segments
//   pass3: chunked causal recurrence per segment seeded with prefix state.

#define Nn   4
#define Ll   8192
#define Hh   16
#define NHh  64          // Nn*Hh
#define CCH  64          // chunk size (positions)
#define LD   68          // LDS row stride (floats): 16B-aligned, 2-way-bank max
#define SLOT 4160        // per-(nh,seg) ws slot: 4096 state + 64 ksum floats
#define EPSF 1e-6f

__device__ __forceinline__ float elu1(float x) {
  // jax.nn.elu(x)+1 : x>=0 -> x+1 ; x<0 -> exp(x)
  return x > 0.f ? x + 1.f : __expf(x);
}

__device__ __forceinline__ void outer4(float (&o)[4][4], const float a[4], const float4 b) {
  const float bb[4] = {b.x, b.y, b.z, b.w};
#pragma unroll
  for (int i = 0; i < 4; ++i)
#pragma unroll
    for (int j = 0; j < 4; ++j)
      o[i][j] = __builtin_fmaf(a[i], bb[j], o[i][j]);
}

// ---------------------------------------------------------------- pass 1
__global__ __launch_bounds__(256, 2) void la_pass1(
    const float* __restrict__ Kg, const float* __restrict__ Vg,
    float* __restrict__ ws, int G, int Lseg) {
  const int bid = blockIdx.x;
  const int nh = bid / G, g = bid % G;
  const int n = nh / Hh, h = nh % Hh;
  const int t = threadIdx.x;
  const int row = t >> 2, q4 = t & 3;
  const int e0 = (t >> 4) * 4, d0 = (t & 15) * 4;

  __shared__ float Kr[64 * 64];  // K[j][e], elu applied
  __shared__ float Vv[64 * 64];  // V[j][d]

  float acc[4][4];
#pragma unroll
  for (int a = 0; a < 4; ++a)
#pragma unroll
    for (int b = 0; b < 4; ++b) acc[a][b] = 0.f;
  float ksum_t = 0.f;

  const int nchunk = Lseg / CCH;
  for (int c = 0; c < nchunk; ++c) {
    const int lbase = g * Lseg + c * CCH;
    const size_t gb = ((size_t)((n * Ll + lbase + row) * Hh + h)) * 64;
#pragma unroll
    for (int u = 0; u < 4; ++u) {
      const int col = u * 16 + q4 * 4;
      float4 kv = *(const float4*)(Kg + gb + col);
      float4 vv = *(const float4*)(Vg + gb + col);
      kv.x = elu1(kv.x); kv.y = elu1(kv.y); kv.z = elu1(kv.z); kv.w = elu1(kv.w);
      *(float4*)(Kr + row * 64 + col) = kv;
      *(float4*)(Vv + row * 64 + col) = vv;
    }
    __syncthreads();
#pragma unroll 4
    for (int j = 0; j < 64; ++j) {
      float4 kv = *(const float4*)(Kr + j * 64 + e0);
      float4 vv = *(const float4*)(Vv + j * 64 + d0);
      const float ka[4] = {kv.x, kv.y, kv.z, kv.w};
      outer4(acc, ka, vv);
    }
    if (t < 64) {
      float s = 0.f;
#pragma unroll 8
      for (int j = 0; j < 64; ++j) s += Kr[j * 64 + t];
      ksum_t += s;
    }
    __syncthreads();
  }
  const size_t slot = (size_t)bid * SLOT;
#pragma unroll
  for (int a = 0; a < 4; ++a) {
    float4 o = make_float4(acc[a][0], acc[a][1], acc[a][2], acc[a][3]);
    *(float4*)(ws + slot + (e0 + a) * 64 + d0) = o;
  }
  if (t < 64) ws[slot + 4096 + t] = ksum_t;
}

// ---------------------------------------------------------------- pass 2
__global__ __launch_bounds__(256) void la_pass2(float* __restrict__ ws, int G) {
  const int nh = blockIdx.x;
  const int t = threadIdx.x;
  float run[17];
#pragma unroll
  for (int u = 0; u < 17; ++u) run[u] = 0.f;
  for (int g = 0; g < G; ++g) {
    const size_t base = (size_t)(nh * G + g) * SLOT;
#pragma unroll
    for (int u = 0; u < 17; ++u) {
      const int idx = u * 256 + t;
      if (idx < SLOT) {
        const float cur = ws[base + idx];
        ws[base + idx] = run[u];   // exclusive prefix
        run[u] += cur;
      }
    }
  }
}

// ---------------------------------------------------------------- pass 3
__global__ __launch_bounds__(256, 2) void la_pass3(
    const float* __restrict__ Qg, const float* __restrict__ Kg,
    const float* __restrict__ Vg, const float* __restrict__ ws,
    float* __restrict__ out, int G, int Lseg, int has_prefix) {
  const int bid = blockIdx.x;
  const int nh = bid / G, g = bid % G;
  const int n = nh / Hh, h = nh % Hh;
  const int t = threadIdx.x;
  const int row = t >> 2, q4 = t & 3;
  const int i0 = (t >> 4) * 4;   // row tile: positions i / state rows e
  const int j0 = (t & 15) * 4;   // col tile: positions j / value dims d

  __shared__ float QS[64 * LD];  // Qt[e][i], later reused as masked scores Sc[i][j]
  __shared__ float Kt[64 * LD];  // Kt[e][j]
  __shared__ float Vv[64 * LD];  // V[j][d]
  __shared__ float St[64 * LD];  // state S[e][d]
  __shared__ float ksum[64];
  __shared__ float zbuf[64];

  const size_t slot = (size_t)bid * SLOT;
#pragma unroll
  for (int u = 0; u < 16; ++u) {
    const int idx = u * 256 + t;
    St[(idx >> 6) * LD + (idx & 63)] = has_prefix ? ws[slot + idx] : 0.f;
  }
  if (t < 64) ksum[t] = has_prefix ? ws[slot + 4096 + t] : 0.f;
  __syncthreads();

  const int nchunk = Lseg / CCH;
  for (int c = 0; c < nchunk; ++c) {
    const int lbase = g * Lseg + c * CCH;
    const size_t gb = ((size_t)((n * Ll + lbase + row) * Hh + h)) * 64;
#pragma unroll
    for (int u = 0; u < 4; ++u) {
      const int col = u * 16 + q4 * 4;
      float4 qv = *(const float4*)(Qg + gb + col);
      float4 kv = *(const float4*)(Kg + gb + col);
      float4 vv = *(const float4*)(Vg + gb + col);
      qv.x = elu1(qv.x); qv.y = elu1(qv.y); qv.z = elu1(qv.z); qv.w = elu1(qv.w);
      kv.x = elu1(kv.x); kv.y = elu1(kv.y); kv.z = elu1(kv.z); kv.w = elu1(kv.w);
      QS[(col + 0) * LD + row] = qv.x;
      QS[(col + 1) * LD + row] = qv.y;
      QS[(col + 2) * LD + row] = qv.z;
      QS[(col + 3) * LD + row] = qv.w;
      Kt[(col + 0) * LD + row] = kv.x;
      Kt[(col + 1) * LD + row] = kv.y;
      Kt[(col + 2) * LD + row] = kv.z;
      Kt[(col + 3) * LD + row] = kv.w;
      *(float4*)(Vv + row * LD + col) = vv;
    }
    __syncthreads();  // B1: tiles staged

    // fused: inter o = Q @ S_prev  and  scores sc = Q @ K^T
    float o[4][4], sc[4][4];
#pragma unroll
    for (int a = 0; a < 4; ++a)
#pragma unroll
      for (int b = 0; b < 4; ++b) { o[a][b] = 0.f; sc[a][b] = 0.f; }
#pragma unroll 4
    for (int e = 0; e < 64; ++e) {
      float4 qv = *(const float4*)(QS + e * LD + i0);
      float4 kv = *(const float4*)(Kt + e * LD + j0);
      float4 sv = *(const float4*)(St + e * LD + j0);
      const float qa[4] = {qv.x, qv.y, qv.z, qv.w};
      outer4(sc, qa, kv);
      outer4(o, qa, sv);
    }
    float dden = 0.f;
    if (t < 64) {
#pragma unroll 8
      for (int e = 0; e < 64; ++e) dden += QS[e * LD + t] * ksum[e];
    }
    __syncthreads();  // B2: all Qt reads done; QS may be overwritten

    // write masked scores into QS (causal: keep j<=i)
#pragma unroll
    for (int a = 0; a < 4; ++a)
#pragma unroll
      for (int b = 0; b < 4; ++b)
        QS[(i0 + a) * LD + (j0 + b)] = (j0 + b <= i0 + a) ? sc[a][b] : 0.f;
    __syncthreads();  // B3: scores visible

    // intra: o += Sc @ V ; state tile update: st += K^T V
    float st[4][4];
#pragma unroll
    for (int a = 0; a < 4; ++a) {
      float4 sv = *(const float4*)(St + (i0 + a) * LD + j0);
      st[a][0] = sv.x; st[a][1] = sv.y; st[a][2] = sv.z; st[a][3] = sv.w;
    }
#pragma unroll 4
    for (int j = 0; j < 64; ++j) {
      float4 vv = *(const float4*)(Vv + j * LD + j0);
      const float sa[4] = {QS[(i0 + 0) * LD + j], QS[(i0 + 1) * LD + j],
                           QS[(i0 + 2) * LD + j], QS[(i0 + 3) * LD + j]};
      const float ka[4] = {Kt[(i0 + 0) * LD + j], Kt[(i0 + 1) * LD + j],
                           Kt[(i0 + 2) * LD + j], Kt[(i0 + 3) * LD + j]};
      outer4(o, sa, vv);
      outer4(st, ka, vv);
    }
#pragma unroll
    for (int a = 0; a < 4; ++a)
      *(float4*)(St + (i0 + a) * LD + j0) =
          make_float4(st[a][0], st[a][1], st[a][2], st[a][3]);

    if (t < 64) {
      float rs = 0.f, ks = 0.f;
#pragma unroll 8
      for (int j = 0; j < 64; ++j) {
        rs += QS[t * LD + j];   // row-sum of masked scores
        ks += Kt[t * LD + j];   // this chunk's K-sum for feature t
      }
      zbuf[t] = 1.f / (dden + rs + EPSF);
      ksum[t] += ks;
    }
    __syncthreads();  // B4: z ready, state updated

#pragma unroll
    for (int a = 0; a < 4; ++a) {
      const float z = zbuf[i0 + a];
      float4 ov = make_float4(o[a][0] * z, o[a][1] * z, o[a][2] * z, o[a][3] * z);
      *(float4*)(out + ((size_t)((n * Ll + lbase + i0 + a) * Hh + h)) * 64 + j0) = ov;
    }
  }
}

// ---------------------------------------------------------------- launch
extern "C" void kernel_launch(void* const* d_in, const int* in_sizes, int n_in,
                              void* d_out, int out_size, void* d_ws, size_t ws_size,
                              hipStream_t stream) {
  (void)in_sizes; (void)n_in; (void)out_size;
  const float* Qg = (const float*)d_in[0];
  const float* Kg = (const float*)d_in[1];
  const float* Vg = (const float*)d_in[2];
  float* out = (float*)d_out;
  float* ws = (float*)d_ws;

  const size_t per_seg = (size_t)NHh * SLOT * sizeof(float);  // bytes per G-layer
  int G = 1;
  if (ws_size >= 16 * per_seg) G = 16;
  else if (ws_size >= 8 * per_seg) G = 8;
  else if (ws_size >= 4 * per_seg) G = 4;
  else if (ws_size >= 2 * per_seg) G = 2;
  const int Lseg = Ll / G;

  if (G > 1) {
    la_pass1<<<NHh * G, 256, 0, stream>>>(Kg, Vg, ws, G, Lseg);
    la_pass2<<<NHh, 256, 0, stream>>>(ws, G);
  }
  la_pass3<<<NHh * G, 256, 0, stream>>>(Qg, Kg, Vg, ws, out, G, Lseg, G > 1 ? 1 : 0);
}

// Round 2
// 522.234 us; speedup vs baseline: 1.2417x; 1.2417x over previous
//
#include <hip/hip_runtime.h>
#include <hip/hip_bf16.h>

// CausalLinearAttention — bf16-MFMA version.
// N=4, L=8192, H=16, E=D=64. 3-pass segment-parallel scan.
// All 64x64x64 matmuls on v_mfma_f32_16x16x32_bf16; state S^T kept in fp32
// MFMA accumulators across chunks (no compounding rounding).

#define Nn   4
#define Ll   8192
#define Hh   16
#define NHh  64
#define CCH  64          // chunk size (positions)
#define LDB  72          // bf16 LDS row stride: 144 B = 16B-multiple, low-conflict
#define SLOT 4160        // per-(nh,seg) ws slot: 4096 state + 64 ksum floats
#define EPSF 1e-6f

typedef __attribute__((ext_vector_type(8))) short short8;   // 8 bf16 = 4 VGPRs
typedef __attribute__((ext_vector_type(4))) float floatx4;  // MFMA accumulator

__device__ __forceinline__ float elu1(float x) {
  return x > 0.f ? x + 1.f : __expf(x);
}

__device__ __forceinline__ floatx4 mfma16(short8 a, short8 b, floatx4 c) {
  return __builtin_amdgcn_mfma_f32_16x16x32_bf16(a, b, c, 0, 0, 0);
}

// load an A/B fragment: row-major [16-row-block][k], 8 consecutive bf16 at
// k = kh*32 + quad*8  (lane m = row within block)
__device__ __forceinline__ short8 frag_ld(const __hip_bfloat16* base, int row,
                                          int kh, int quad) {
  return *(const short8*)(base + row * LDB + kh * 32 + quad * 8);
}

// pack 4 floats -> 4 bf16, single 8-byte LDS write (dst 8B-aligned: col%4==0)
__device__ __forceinline__ void st4bf(__hip_bfloat16* dst, float4 v) {
  union { __hip_bfloat16 h[4]; uint2 u; } pk;
  pk.h[0] = __float2bfloat16(v.x); pk.h[1] = __float2bfloat16(v.y);
  pk.h[2] = __float2bfloat16(v.z); pk.h[3] = __float2bfloat16(v.w);
  *(uint2*)dst = pk.u;
}

// ---------------------------------------------------------------- pass 1
// per-(nh,seg): partial S^T = V^T K (64x64) and ksum (64), written to ws.
__global__ __launch_bounds__(256, 4) void la_pass1(
    const float* __restrict__ Kg, const float* __restrict__ Vg,
    float* __restrict__ ws, int G, int Lseg) {
  const int bid = blockIdx.x;
  const int nh = bid / G, g = bid % G;
  const int n = nh / Hh, h = nh % Hh;
  const int t = threadIdx.x;
  const int wave = t >> 6, lane = t & 63, m = lane & 15, quad = lane >> 4;
  const int row = t >> 2, q4 = t & 3;

  __shared__ __hip_bfloat16 Ktb[64 * LDB];  // K^T [e][j]
  __shared__ __hip_bfloat16 Vtb[64 * LDB];  // V^T [d][j]

  floatx4 Sacc[4];  // S^T tiles: rows d = 16*wave + quad*4 + r, cols e = 16*b + m
  const floatx4 z4 = {0.f, 0.f, 0.f, 0.f};
#pragma unroll
  for (int b = 0; b < 4; ++b) Sacc[b] = z4;
  float ksr = 0.f;

  const int nchunk = Lseg / CCH;
  for (int c = 0; c < nchunk; ++c) {
    const size_t gb = ((size_t)((n * Ll + g * Lseg + c * CCH + row) * Hh + h)) * 64;
#pragma unroll
    for (int u = 0; u < 4; ++u) {
      const int col = u * 16 + q4 * 4;
      float4 kv = *(const float4*)(Kg + gb + col);
      float4 vv = *(const float4*)(Vg + gb + col);
      kv.x = elu1(kv.x); kv.y = elu1(kv.y); kv.z = elu1(kv.z); kv.w = elu1(kv.w);
      Ktb[(col + 0) * LDB + row] = __float2bfloat16(kv.x);
      Ktb[(col + 1) * LDB + row] = __float2bfloat16(kv.y);
      Ktb[(col + 2) * LDB + row] = __float2bfloat16(kv.z);
      Ktb[(col + 3) * LDB + row] = __float2bfloat16(kv.w);
      Vtb[(col + 0) * LDB + row] = __float2bfloat16(vv.x);
      Vtb[(col + 1) * LDB + row] = __float2bfloat16(vv.y);
      Vtb[(col + 2) * LDB + row] = __float2bfloat16(vv.z);
      Vtb[(col + 3) * LDB + row] = __float2bfloat16(vv.w);
    }
    __syncthreads();
    const short8 a0 = frag_ld(Vtb, 16 * wave + m, 0, quad);
    const short8 a1 = frag_ld(Vtb, 16 * wave + m, 1, quad);
#pragma unroll
    for (int b = 0; b < 4; ++b) {
      Sacc[b] = mfma16(a0, frag_ld(Ktb, 16 * b + m, 0, quad), Sacc[b]);
      Sacc[b] = mfma16(a1, frag_ld(Ktb, 16 * b + m, 1, quad), Sacc[b]);
    }
    if (t < 64) {
      float s = 0.f;
#pragma unroll 8
      for (int j = 0; j < 64; ++j) s += (float)Ktb[t * LDB + j];
      ksr += s;
    }
    __syncthreads();
  }
  const size_t slot = (size_t)bid * SLOT;
#pragma unroll
  for (int b = 0; b < 4; ++b)
#pragma unroll
    for (int r = 0; r < 4; ++r) {
      const int d = 16 * wave + quad * 4 + r, e = 16 * b + m;
      ws[slot + d * 64 + e] = Sacc[b][r];
    }
  if (t < 64) ws[slot + 4096 + t] = ksr;
}

// ---------------------------------------------------------------- pass 2
__global__ __launch_bounds__(256) void la_pass2(float* __restrict__ ws, int G) {
  const int nh = blockIdx.x;
  const int t = threadIdx.x;
  float run[17];
#pragma unroll
  for (int u = 0; u < 17; ++u) run[u] = 0.f;
  for (int g = 0; g < G; ++g) {
    const size_t base = (size_t)(nh * G + g) * SLOT;
#pragma unroll
    for (int u = 0; u < 17; ++u) {
      const int idx = u * 256 + t;
      if (idx < SLOT) {
        const float cur = ws[base + idx];
        ws[base + idx] = run[u];
        run[u] += cur;
      }
    }
  }
}

// ---------------------------------------------------------------- pass 3
__global__ __launch_bounds__(256, 3) void la_pass3(
    const float* __restrict__ Qg, const float* __restrict__ Kg,
    const float* __restrict__ Vg, const float* __restrict__ ws,
    float* __restrict__ out, int G, int Lseg, int has_prefix) {
  const int bid = blockIdx.x;
  const int nh = bid / G, g = bid % G;
  const int n = nh / Hh, h = nh % Hh;
  const int t = threadIdx.x;
  const int wave = t >> 6, lane = t & 63, m = lane & 15, quad = lane >> 4;
  const int row = t >> 2, q4 = t & 3;

  __shared__ __hip_bfloat16 QPb[64 * LDB];  // Q [i][e], then masked P [i][j]
  __shared__ __hip_bfloat16 Kb [64 * LDB];  // K [j][e]
  __shared__ __hip_bfloat16 Ktb[64 * LDB];  // K^T [e][j]
  __shared__ __hip_bfloat16 Vtb[64 * LDB];  // V^T [d][j]
  __shared__ __hip_bfloat16 Stb[64 * LDB];  // bf16 snapshot of S^T [d][e]
  __shared__ float ksum[64];
  __shared__ float zS[64];

  const size_t slot = (size_t)bid * SLOT;
  floatx4 Sacc[4];  // persistent S^T: rows d = 16*wave+quad*4+r, cols e = 16*b+m
  const floatx4 z4 = {0.f, 0.f, 0.f, 0.f};
#pragma unroll
  for (int b = 0; b < 4; ++b) {
    Sacc[b] = z4;
    if (has_prefix) {
#pragma unroll
      for (int r = 0; r < 4; ++r)
        Sacc[b][r] = ws[slot + (16 * wave + quad * 4 + r) * 64 + 16 * b + m];
    }
  }
  if (t < 64) ksum[t] = has_prefix ? ws[slot + 4096 + t] : 0.f;

  const int nchunk = Lseg / CCH;
  for (int c = 0; c < nchunk; ++c) {
    const int lbase = g * Lseg + c * CCH;
    const size_t gb = ((size_t)((n * Ll + lbase + row) * Hh + h)) * 64;
#pragma unroll
    for (int u = 0; u < 4; ++u) {
      const int col = u * 16 + q4 * 4;
      float4 qv = *(const float4*)(Qg + gb + col);
      float4 kv = *(const float4*)(Kg + gb + col);
      float4 vv = *(const float4*)(Vg + gb + col);
      qv.x = elu1(qv.x); qv.y = elu1(qv.y); qv.z = elu1(qv.z); qv.w = elu1(qv.w);
      kv.x = elu1(kv.x); kv.y = elu1(kv.y); kv.z = elu1(kv.z); kv.w = elu1(kv.w);
      st4bf(&QPb[row * LDB + col], qv);
      st4bf(&Kb [row * LDB + col], kv);
      Ktb[(col + 0) * LDB + row] = __float2bfloat16(kv.x);
      Ktb[(col + 1) * LDB + row] = __float2bfloat16(kv.y);
      Ktb[(col + 2) * LDB + row] = __float2bfloat16(kv.z);
      Ktb[(col + 3) * LDB + row] = __float2bfloat16(kv.w);
      Vtb[(col + 0) * LDB + row] = __float2bfloat16(vv.x);
      Vtb[(col + 1) * LDB + row] = __float2bfloat16(vv.y);
      Vtb[(col + 2) * LDB + row] = __float2bfloat16(vv.z);
      Vtb[(col + 3) * LDB + row] = __float2bfloat16(vv.w);
    }
    // snapshot state to bf16 for the inter product
#pragma unroll
    for (int b = 0; b < 4; ++b)
#pragma unroll
      for (int r = 0; r < 4; ++r)
        Stb[(16 * wave + quad * 4 + r) * LDB + 16 * b + m] =
            __float2bfloat16(Sacc[b][r]);
    __syncthreads();  // B1: tiles + snapshot staged

    // m1: Sc = Q K^T ; m2: O = Q S_prev
    const short8 qa0 = frag_ld(QPb, 16 * wave + m, 0, quad);
    const short8 qa1 = frag_ld(QPb, 16 * wave + m, 1, quad);
    floatx4 sc[4], O[4];
#pragma unroll
    for (int b = 0; b < 4; ++b) {
      sc[b] = mfma16(qa0, frag_ld(Kb, 16 * b + m, 0, quad), z4);
      sc[b] = mfma16(qa1, frag_ld(Kb, 16 * b + m, 1, quad), sc[b]);
      O[b]  = mfma16(qa0, frag_ld(Stb, 16 * b + m, 0, quad), z4);
      O[b]  = mfma16(qa1, frag_ld(Stb, 16 * b + m, 1, quad), O[b]);
    }
    float dden = 0.f;
    if (t < 64) {
#pragma unroll 8
      for (int e = 0; e < 64; ++e) dden += (float)QPb[t * LDB + e] * ksum[e];
    }
    __syncthreads();  // B2: Q reads done; QPb may become P

    // causal mask, write P (bf16) in A-operand-friendly row-major layout
#pragma unroll
    for (int b = 0; b < 4; ++b)
#pragma unroll
      for (int r = 0; r < 4; ++r) {
        const int i = 16 * wave + quad * 4 + r, j = 16 * b + m;
        QPb[i * LDB + j] = __float2bfloat16(j <= i ? sc[b][r] : 0.f);
      }
    __syncthreads();  // B3: P visible

    // m3: O += P V ; m4: Sacc += V^T K
    const short8 pa0 = frag_ld(QPb, 16 * wave + m, 0, quad);
    const short8 pa1 = frag_ld(QPb, 16 * wave + m, 1, quad);
    const short8 va0 = frag_ld(Vtb, 16 * wave + m, 0, quad);
    const short8 va1 = frag_ld(Vtb, 16 * wave + m, 1, quad);
#pragma unroll
    for (int b = 0; b < 4; ++b) {
      O[b]    = mfma16(pa0, frag_ld(Vtb, 16 * b + m, 0, quad), O[b]);
      O[b]    = mfma16(pa1, frag_ld(Vtb, 16 * b + m, 1, quad), O[b]);
      Sacc[b] = mfma16(va0, frag_ld(Ktb, 16 * b + m, 0, quad), Sacc[b]);
      Sacc[b] = mfma16(va1, frag_ld(Ktb, 16 * b + m, 1, quad), Sacc[b]);
    }
    if (t < 64) {
      float rs = 0.f, ks = 0.f;
#pragma unroll 8
      for (int j = 0; j < 64; ++j) {
        rs += (float)QPb[t * LDB + j];
        ks += (float)Ktb[t * LDB + j];
      }
      zS[t] = 1.f / (dden + rs + EPSF);
      ksum[t] += ks;
    }
    __syncthreads();  // B4: z ready; all LDS reads of this chunk done

    const size_t ob = ((size_t)((n * Ll + lbase) * Hh + h)) * 64;
#pragma unroll
    for (int r = 0; r < 4; ++r) {
      const int i = 16 * wave + quad * 4 + r;
      const float z = zS[i];
#pragma unroll
      for (int b = 0; b < 4; ++b)
        out[ob + (size_t)i * (Hh * 64) + 16 * b + m] = O[b][r] * z;
    }
  }
}

// ---------------------------------------------------------------- launch
extern "C" void kernel_launch(void* const* d_in, const int* in_sizes, int n_in,
                              void* d_out, int out_size, void* d_ws, size_t ws_size,
                              hipStream_t stream) {
  (void)in_sizes; (void)n_in; (void)out_size;
  const float* Qg = (const float*)d_in[0];
  const float* Kg = (const float*)d_in[1];
  const float* Vg = (const float*)d_in[2];
  float* out = (float*)d_out;
  float* ws = (float*)d_ws;

  const size_t per_seg = (size_t)NHh * SLOT * sizeof(float);
  int G = 1;
  if (ws_size >= 16 * per_seg) G = 16;
  else if (ws_size >= 8 * per_seg) G = 8;
  else if (ws_size >= 4 * per_seg) G = 4;
  else if (ws_size >= 2 * per_seg) G = 2;
  const int Lseg = Ll / G;

  if (G > 1) {
    la_pass1<<<NHh * G, 256, 0, stream>>>(Kg, Vg, ws, G, Lseg);
    la_pass2<<<NHh, 256, 0, stream>>>(ws, G);
  }
  la_pass3<<<NHh * G, 256, 0, stream>>>(Qg, Kg, Vg, ws, out, G, Lseg, G > 1 ? 1 : 0);
}